// Round 8
// baseline (251.646 us; speedup 1.0000x reference)
//
#include <hip/hip_runtime.h>
#include <hip/hip_bf16.h>
#include <math.h>

// MoLE layer: out = gelu(x @ base_w^T + base_b) + top1_w * (gelu(x @ A[e]) @ B[e])
// probs = softmax(x @ gate_w^T + gate_b)
// T=8192 tokens, D=2048, E=8 experts, RANK=16.
//
// Pipeline (3 kernels), dependency-ordered by dispatch boundaries:
//  k1 cvt_logits: blocks [0,1024) = token blocks (8 tokens each): convert x
//     fp32->bf16 + fp32 logits with gate_w in REGISTERS (reduce-scatter
//     reduction). Blocks [1024,1152) = Ab transpose lora_A -> Ab [128][2048]
//     (MUST be here: its consumer is hsel in k2 — moving it into k2 was a
//     same-dispatch read/write race, R7 bug).
//  k2 hselx: blocks [0,512) = dense H = Xb @ Ab over ALL experts, 32x64 tile,
//     BK=256 quarter-major staging, 8-slot XOR swizzle; epilogue writes
//     one-hot A2 = (idx==e)*w*gelu(H). Blocks [512,2560) = base_w cvt;
//     [2560,2816) = Bt transpose — both consumed only by k3 (safe).
//  k3 gemm: 128x128 bf16 MFMA GEMM, BK=64 2-barrier staging (measured local
//     optimum: R1 8-phase port and R5 3-ring both regressed). 8-slot XOR LDS
//     (conflict-free). Grid m-fastest: XCD = m%8 keeps A-slab L2-resident
//     (FETCH 151->77MB, R4-verified). __launch_bounds__(256,4): target 64
//     arch VGPR + 64 acc = 128 unified -> 4 blocks/CU -> grid 1024 = 4x256,
//     zero tail (was 3/CU with a 256-block tail at 1/CU).
//     Epilogue: +bias, GELU, LoRA as 4 extra K=32 MFMAs from A2/Bt, fp32 out.

#define DIM   2048
#define RANK  16
#define NEXP  8
#define NTOK  8192
#define KLORA 128   // NEXP*RANK

typedef __hip_bfloat16 bf16;
typedef __attribute__((ext_vector_type(8))) short short8;  // 8 bf16 = 4 VGPRs
typedef __attribute__((ext_vector_type(4))) float float4v;

typedef const __attribute__((address_space(1))) void* gptr_t;
typedef __attribute__((address_space(3))) void*       sptr_t;

__device__ __forceinline__ void async_ld16(const bf16* g, bf16* l) {
    __builtin_amdgcn_global_load_lds((gptr_t)g, (sptr_t)l, 16, 0, 0);
}

// tanh-approx GELU: |err vs erf-gelu| <= ~3e-3, well under 0.1 threshold
__device__ __forceinline__ float gelu_fast(float x) {
    float t = 0.7978845608028654f * (x + 0.044715f * x * x * x);
    t = fminf(fmaxf(t, -10.0f), 10.0f);
    float e = __expf(2.0f * t);
    float th = (e - 1.0f) / (e + 1.0f);
    return 0.5f * x * (1.0f + th);
}

__device__ __forceinline__ short8 pack8(float4 v0, float4 v1) {
    union { bf16 h[8]; short8 v; } u;
    u.h[0] = __float2bfloat16(v0.x); u.h[1] = __float2bfloat16(v0.y);
    u.h[2] = __float2bfloat16(v0.z); u.h[3] = __float2bfloat16(v0.w);
    u.h[4] = __float2bfloat16(v1.x); u.h[5] = __float2bfloat16(v1.y);
    u.h[6] = __float2bfloat16(v1.z); u.h[7] = __float2bfloat16(v1.w);
    return u.v;
}

// --------------------------------------------------------- cvt+logits kernel
// blocks [0,1024): 8 tokens each: convert x->Xb + fp32 logits/softmax/argmax.
// blocks [1024,1152): Ab transpose lora_A [8][2048][16] -> Ab [128][2048].
__global__ __launch_bounds__(256) void cvt_logits_kernel(
    const float* __restrict__ x, const float* __restrict__ gate_w,
    const float* __restrict__ gate_b, const float* __restrict__ lora_A,
    bf16* __restrict__ Xb, bf16* __restrict__ Ab,
    float* __restrict__ probs, int* __restrict__ idx_out, float* __restrict__ w_out)
{
    __shared__ float buf[2560];
    const int b   = blockIdx.x;
    const int tid = threadIdx.x;

    if (b < 1024) {
        const int t0 = b * 8;
        float4 g0[NEXP], g1[NEXP];      // gate_w slice: 8 experts x 8 floats
        #pragma unroll
        for (int e = 0; e < NEXP; e++) {
            const float* wr = gate_w + (size_t)e * DIM + tid * 8;
            g0[e] = *(const float4*)wr;
            g1[e] = *(const float4*)(wr + 4);
        }
        const int wave = tid >> 6, lane = tid & 63;
        // expert owned by this lane after reduce-scatter: bitrev3(lane&7)
        const int eown = ((lane & 1) << 2) | (lane & 2) | ((lane & 4) >> 2);
        #pragma unroll
        for (int tt = 0; tt < 8; tt++) {
            const int t = t0 + tt;
            const float* xr = x + (size_t)t * DIM + tid * 8;
            float4 v0 = *(const float4*)xr;
            float4 v1 = *(const float4*)(xr + 4);
            *(short8*)(Xb + (size_t)t * DIM + tid * 8) = pack8(v0, v1);
            float a[NEXP];
            #pragma unroll
            for (int e = 0; e < NEXP; e++) {
                a[e] = v0.x * g0[e].x + v0.y * g0[e].y + v0.z * g0[e].z + v0.w * g0[e].w
                     + v1.x * g1[e].x + v1.y * g1[e].y + v1.z * g1[e].z + v1.w * g1[e].w;
            }
            // reduce-scatter over the expert dim within 8-lane groups:
            float b4[4];
            #pragma unroll
            for (int i = 0; i < 4; i++) {
                float send = (lane & 1) ? a[i]     : a[i + 4];
                float keep = (lane & 1) ? a[i + 4] : a[i];
                b4[i] = keep + __shfl_xor(send, 1);
            }
            float b2[2];
            #pragma unroll
            for (int i = 0; i < 2; i++) {
                float send = (lane & 2) ? b4[i]     : b4[i + 2];
                float keep = (lane & 2) ? b4[i + 2] : b4[i];
                b2[i] = keep + __shfl_xor(send, 2);
            }
            float send3 = (lane & 4) ? b2[0] : b2[1];
            float keep3 = (lane & 4) ? b2[1] : b2[0];
            float s = keep3 + __shfl_xor(send3, 4);
            s += __shfl_xor(s, 8);
            s += __shfl_xor(s, 16);
            s += __shfl_xor(s, 32);
            if (lane < NEXP) buf[tt * 32 + wave * NEXP + eown] = s;
        }
        __syncthreads();
        if (tid < 8) {                  // thread tid finalizes token t0+tid
            const int t = t0 + tid;
            float l[NEXP]; float mx = -1e30f;
            #pragma unroll
            for (int e = 0; e < NEXP; e++) {
                l[e] = buf[tid * 32 + e] + buf[tid * 32 + 8 + e]
                     + buf[tid * 32 + 16 + e] + buf[tid * 32 + 24 + e] + gate_b[e];
                mx = fmaxf(mx, l[e]);
            }
            float sum = 0.f;
            #pragma unroll
            for (int e = 0; e < NEXP; e++) { l[e] = __expf(l[e] - mx); sum += l[e]; }
            float inv = 1.0f / sum;
            int es = 0; float best = l[0];
            #pragma unroll
            for (int e = 1; e < NEXP; e++) if (l[e] > best) { best = l[e]; es = e; }
            #pragma unroll
            for (int e = 0; e < NEXP; e++) probs[(size_t)t * NEXP + e] = l[e] * inv;
            idx_out[t] = es;
            w_out[t]   = best * inv;
        }
    } else {
        // ---- Ab transpose: lora_A [8][2048][16] -> Ab [128][2048]
        int bb = b - 1024;
        int e = bb >> 4, k0 = (bb & 15) * 128;
        const float* src = lora_A + (size_t)e * DIM * RANK;
        {
            int k = tid >> 2, r4 = (tid & 3) * 4;
            float4 va = *(const float4*)(src + (size_t)(k0 + k) * RANK + r4);
            float4 vb = *(const float4*)(src + (size_t)(k0 + k + 64) * RANK + r4);
            *(float4*)(buf + k * 20 + r4)        = va;
            *(float4*)(buf + (k + 64) * 20 + r4) = vb;
        }
        __syncthreads();
        {
            int r = tid >> 4, kx = (tid & 15) * 8;
            bf16* dst = Ab + (size_t)(e * 16 + r) * DIM + k0 + kx;
            #pragma unroll
            for (int i = 0; i < 8; i++) dst[i] = __float2bfloat16(buf[(kx + i) * 20 + r]);
        }
    }
}

// ---------------------------------------------------------------- hselx kernel
// blocks [0,512): H = Xb @ Ab (all experts, K=2048), 32x64 tile, BK=256,
//   quarter-major LDS As[4][32][64] / Bs[4][64][64], proven 8-slot XOR within
//   each quarter. Epilogue: A2[t][jcol] = (idx[t]==jcol>>4) * w[t] * gelu(H).
// blocks [512,2560): base_w fp32->bf16 convert (8 floats/thread).
// blocks [2560,2816): Bt transpose lora_B [128][2048] -> Bt [2048][128].
// (Wb and Bt are consumed only by the gemm, a later dispatch — safe.)
__global__ __launch_bounds__(256) void hselx_kernel(
    const bf16* __restrict__ Xb, const bf16* __restrict__ Ab,
    const int* __restrict__ idx, const float* __restrict__ wsel,
    const float* __restrict__ base_w, const float* __restrict__ lora_B,
    bf16* __restrict__ A2, bf16* __restrict__ Wb, bf16* __restrict__ Bt)
{
    __shared__ bf16 As[4 * 32 * 64];    // 16 KB [quarter][row][64]
    __shared__ bf16 Bs[4 * 64 * 64];    // 32 KB [quarter][row][64]
    float* buf = (float*)As;            // scratch overlay for transpose blocks
    const int bid = blockIdx.x;
    const int tid = threadIdx.x;

    if (bid < 512) {
        const int wave = tid >> 6, lane = tid & 63;
        const int m0 = (bid & 255) * 32;
        const int n0 = (bid >> 8) * 64;
        const int col = lane & 15, quad = lane >> 4;

        const int kc = ((tid & 7) ^ ((tid >> 3) & 7)) * 8;   // within-quarter
        const int sr = tid >> 3;                       // 0..31
        const bf16* gA  = Xb + (size_t)(m0 + sr) * DIM + kc;
        const bf16* gB0 = Ab + (size_t)(n0 + sr) * DIM + kc;
        const bf16* gB1 = gB0 + (size_t)32 * DIM;      // rows 32..63
        bf16* lA = As + wave * 512;                    // wave-uniform LDS base
        bf16* lB = Bs + wave * 512;

        int slot[2];
        #pragma unroll
        for (int p = 0; p < 2; p++)
            slot[p] = (((p << 2) | quad) ^ (col & 7)) * 8;
        const bf16* pa = As + col * 64;                // + h*2048 + i*1024
        const bf16* pb = Bs + (wave * 16 + col) * 64;  // + h*4096

        float4v acc[2] = {};
        for (int k0 = 0; k0 < DIM; k0 += 256) {
            __syncthreads();
            #pragma unroll
            for (int h = 0; h < 4; h++) {
                async_ld16(gA  + k0 + h * 64, lA + h * 2048);
                async_ld16(gB0 + k0 + h * 64, lB + h * 4096);
                async_ld16(gB1 + k0 + h * 64, lB + h * 4096 + 2048);
            }
            __syncthreads();
            #pragma unroll
            for (int ks = 0; ks < 8; ks++) {
                const int h = ks >> 1, p = ks & 1;
                short8 a0 = *(const short8*)(pa + h * 2048 + slot[p]);
                short8 a1 = *(const short8*)(pa + h * 2048 + 1024 + slot[p]);
                short8 b0 = *(const short8*)(pb + h * 4096 + slot[p]);
                acc[0] = __builtin_amdgcn_mfma_f32_16x16x32_bf16(a0, b0, acc[0], 0, 0, 0);
                acc[1] = __builtin_amdgcn_mfma_f32_16x16x32_bf16(a1, b0, acc[1], 0, 0, 0);
            }
        }

        const int jcol = n0 + wave * 16 + col;
        const int ej   = jcol >> 4;
        #pragma unroll
        for (int i = 0; i < 2; i++) {
            int rbase = m0 + i * 16 + quad * 4;
            #pragma unroll
            for (int r = 0; r < 4; r++) {
                int t = rbase + r;
                float v = (idx[t] == ej) ? gelu_fast(acc[i][r]) * wsel[t] : 0.0f;
                A2[(size_t)t * KLORA + jcol] = __float2bfloat16(v);
            }
        }
    } else if (bid < 512 + 2048) {
        // ---- base_w convert: 8 floats/thread ----
        size_t v = ((size_t)(bid - 512) * 256 + tid) * 8;
        float4 v0 = *(const float4*)(base_w + v);
        float4 v1 = *(const float4*)(base_w + v + 4);
        *(short8*)(Wb + v) = pack8(v0, v1);
    } else {
        // ---- Bt transpose: lora_B [128][2048] -> Bt [2048][128], 32x32 tile
        int bb = bid - 512 - 2048;
        int kk0 = (bb >> 6) * 32, j0 = (bb & 63) * 32;
        {   // read coalesced along j
            int r = tid >> 3, c4 = (tid & 7) * 4;
            float4 val = *(const float4*)(lora_B + (size_t)(kk0 + r) * DIM + j0 + c4);
            *(float4*)(buf + r * 36 + c4) = val;
        }
        __syncthreads();
        {   // write coalesced along kk
            int j = tid >> 3, k4 = (tid & 7) * 4;
            bf16* dst = Bt + (size_t)(j0 + j) * KLORA + kk0 + k4;
            #pragma unroll
            for (int i = 0; i < 4; i++) dst[i] = __float2bfloat16(buf[(k4 + i) * 36 + j]);
        }
    }
}

// --------------------------------------------------------------- GEMM kernel
// BK=64 staging (32 barrier rounds), two K=32 MFMA passes per staged buffer.
// Grid m-fastest (dim3(64,16)): XCD = m%8 -> A-slab L2-resident.
// __launch_bounds__(256,4): target 64 arch VGPR so 64+64acc=128 unified ->
// 4 blocks/CU -> 1024 blocks = 4x256 exactly, no tail.
__global__ __launch_bounds__(256, 4) void gemm_kernel(
    const bf16* __restrict__ Xb, const bf16* __restrict__ Wb,
    const float* __restrict__ base_b,
    const bf16* __restrict__ A2, const bf16* __restrict__ Bt,
    float* __restrict__ out)
{
    __shared__ bf16 As[128 * 64];   // 16 KB
    __shared__ bf16 Bs[128 * 64];   // 16 KB
    const int tid  = threadIdx.x;
    const int wave = tid >> 6, lane = tid & 63;
    const int wm = wave >> 1, wn = wave & 1;
    const int m0 = blockIdx.x * 128;    // m fastest: XCD = m%8 (A-slab locality)
    const int n0 = blockIdx.y * 128;
    const int col = lane & 15, quad = lane >> 4;

    // staging: 1024 16B chunks per tile, 4 rounds of 256 threads.
    // LDS slot (tid&7) of row (tid>>3)+32u holds global k-chunk (tid&7)^((tid>>3)&7)
    const int kc = (((tid & 7) ^ ((tid >> 3) & 7))) * 8;
    const int r0 = tid >> 3;            // 0..31
    const bf16* gA0 = Xb + (size_t)(m0 + r0) * DIM + kc;
    const bf16* gB0 = Wb + (size_t)(n0 + r0) * DIM + kc;
    bf16* lA = As + wave * 512;         // +2048 per round
    bf16* lB = Bs + wave * 512;

    // frag read: row = wm*64+i*16+col (row&7 == col&7); slot = (4s+quad)^(col&7)
    const int sl0 = (quad        ^ (col & 7)) * 8;
    const int sl1 = ((quad | 4)  ^ (col & 7)) * 8;
    const bf16* paA = As + (wm * 64 + col) * 64;
    const bf16* pbB = Bs + (wn * 64 + col) * 64;

    float4v acc[4][4] = {};

    for (int k0 = 0; k0 < DIM; k0 += 64) {
        __syncthreads();
        const bf16* ga = gA0 + k0;
        const bf16* gb = gB0 + k0;
        async_ld16(ga,                       lA);
        async_ld16(ga + (size_t)32 * DIM,    lA + 2048);
        async_ld16(ga + (size_t)64 * DIM,    lA + 4096);
        async_ld16(ga + (size_t)96 * DIM,    lA + 6144);
        async_ld16(gb,                       lB);
        async_ld16(gb + (size_t)32 * DIM,    lB + 2048);
        async_ld16(gb + (size_t)64 * DIM,    lB + 4096);
        async_ld16(gb + (size_t)96 * DIM,    lB + 6144);
        __syncthreads();
        {   // K-step 0 (k0 .. k0+32)
            short8 a[4], b[4];
            #pragma unroll
            for (int i = 0; i < 4; i++) a[i] = *(const short8*)(paA + i * 1024 + sl0);
            #pragma unroll
            for (int j = 0; j < 4; j++) b[j] = *(const short8*)(pbB + j * 1024 + sl0);
            #pragma unroll
            for (int i = 0; i < 4; i++)
                #pragma unroll
                for (int j = 0; j < 4; j++)
                    acc[i][j] = __builtin_amdgcn_mfma_f32_16x16x32_bf16(
                        a[i], b[j], acc[i][j], 0, 0, 0);
        }
        {   // K-step 1 (k0+32 .. k0+64)
            short8 a[4], b[4];
            #pragma unroll
            for (int i = 0; i < 4; i++) a[i] = *(const short8*)(paA + i * 1024 + sl1);
            #pragma unroll
            for (int j = 0; j < 4; j++) b[j] = *(const short8*)(pbB + j * 1024 + sl1);
            #pragma unroll
            for (int i = 0; i < 4; i++)
                #pragma unroll
                for (int j = 0; j < 4; j++)
                    acc[i][j] = __builtin_amdgcn_mfma_f32_16x16x32_bf16(
                        a[i], b[j], acc[i][j], 0, 0, 0);
        }
    }

    // epilogue 1: bias + GELU (C/D: row = quad*4+reg, col = lane&15)
    float bias[4];
    #pragma unroll
    for (int j = 0; j < 4; j++) bias[j] = base_b[n0 + wn * 64 + j * 16 + col];
    #pragma unroll
    for (int i = 0; i < 4; i++)
        #pragma unroll
        for (int j = 0; j < 4; j++)
            #pragma unroll
            for (int r = 0; r < 4; r++)
                acc[i][j][r] = gelu_fast(acc[i][j][r] + bias[j]);

    // epilogue 2: LoRA as K=128 MFMA extension (4 steps of K=32)
    const bf16* pea = A2 + (size_t)(m0 + wm * 64 + col) * KLORA + quad * 8;
    const bf16* peb = Bt + (size_t)(n0 + wn * 64 + col) * KLORA + quad * 8;
    #pragma unroll
    for (int ks = 0; ks < 4; ks++) {
        short8 ea[4], eb[4];
        #pragma unroll
        for (int i = 0; i < 4; i++)
            ea[i] = *(const short8*)(pea + i * 16 * KLORA + ks * 32);
        #pragma unroll
        for (int j = 0; j < 4; j++)
            eb[j] = *(const short8*)(peb + j * 16 * KLORA + ks * 32);
        #pragma unroll
        for (int i = 0; i < 4; i++)
            #pragma unroll
            for (int j = 0; j < 4; j++)
                acc[i][j] = __builtin_amdgcn_mfma_f32_16x16x32_bf16(
                    ea[i], eb[j], acc[i][j], 0, 0, 0);
    }

    // store fp32
    #pragma unroll
    for (int i = 0; i < 4; i++) {
        #pragma unroll
        for (int j = 0; j < 4; j++) {
            int tt = m0 + wm * 64 + i * 16 + quad * 4;
            int jj = n0 + wn * 64 + j * 16 + col;
            float* po = out + (size_t)tt * DIM + jj;
            #pragma unroll
            for (int r = 0; r < 4; r++) po[(size_t)r * DIM] = acc[i][j][r];
        }
    }
}

// ------------------------------------------------------------------- launch
extern "C" void kernel_launch(void* const* d_in, const int* in_sizes, int n_in,
                              void* d_out, int out_size, void* d_ws, size_t ws_size,
                              hipStream_t stream)
{
    (void)in_sizes; (void)n_in; (void)out_size; (void)ws_size;
    const float* x      = (const float*)d_in[0];
    const float* gate_w = (const float*)d_in[1];
    const float* gate_b = (const float*)d_in[2];
    const float* base_w = (const float*)d_in[3];
    const float* base_b = (const float*)d_in[4];
    const float* lora_A = (const float*)d_in[5];
    const float* lora_B = (const float*)d_in[6];

    float* out   = (float*)d_out;                    // [8192, 2048]
    float* probs = out + (size_t)NTOK * DIM;         // [8192, 8]

    // workspace layout (~45.2 MB)
    char* ws = (char*)d_ws;
    bf16*  Xb   = (bf16*)ws;                          // 33,554,432 B
    bf16*  Wb   = (bf16*)(ws + 33554432);             //  8,388,608 B
    bf16*  A2   = (bf16*)(ws + 41943040);             //  2,097,152 B
    bf16*  Bt   = (bf16*)(ws + 44040192);             //    524,288 B
    bf16*  Ab   = (bf16*)(ws + 44564480);             //    524,288 B
    int*   idx  = (int*) (ws + 45088768);             //     32,768 B
    float* wsel = (float*)(ws + 45121536);            //     32,768 B

    cvt_logits_kernel<<<1024 + 128, 256, 0, stream>>>(
        x, gate_w, gate_b, lora_A, Xb, Ab, probs, idx, wsel);
    hselx_kernel<<<512 + 2048 + 256, 256, 0, stream>>>(
        Xb, Ab, idx, wsel, base_w, lora_B, A2, Wb, Bt);
    gemm_kernel<<<dim3(64, 16), 256, 0, stream>>>(Xb, Wb, base_b, A2, Bt, out);
}